// Round 10
// baseline (450.708 us; speedup 1.0000x reference)
//
#include <hip/hip_runtime.h>

#define N_NODES 50000
#define E_EDGES 800000
#define SLOPE 0.01f
#define SS ((size_t)N_NODES * 64)   // slice stride (ushort elems) for sliced hb [4][N][64]

typedef __attribute__((ext_vector_type(8))) short bf16x8;
typedef __attribute__((ext_vector_type(4))) float floatx4;
typedef __attribute__((ext_vector_type(4))) float f32x4;
typedef __attribute__((ext_vector_type(2))) float f32x2;
typedef __attribute__((ext_vector_type(2))) unsigned int u32x2;
typedef __attribute__((ext_vector_type(4))) unsigned int u32x4;

__device__ __forceinline__ unsigned short f2bf(float f) {
    unsigned u = __builtin_bit_cast(unsigned, f);
    unsigned r = (u + 0x7FFFu + ((u >> 16) & 1u)) >> 16;
    return (unsigned short)r;
}
__device__ __forceinline__ float bf2f(unsigned short h) {
    unsigned u = ((unsigned)h) << 16;
    return __builtin_bit_cast(float, u);
}
__device__ __forceinline__ float blo(unsigned u) { return __builtin_bit_cast(float, u << 16); }
__device__ __forceinline__ float bhi(unsigned u) { return __builtin_bit_cast(float, u & 0xFFFF0000u); }
__device__ __forceinline__ f32x2 up2(unsigned u) {
    f32x2 t; t.x = blo(u); t.y = bhi(u); return t;
}

// packed accumulate: v_pk_add_f32
__device__ __forceinline__ void acc8p(uint4 v, f32x2 a[4]) {
    a[0] += up2(v.x); a[1] += up2(v.y); a[2] += up2(v.z); a[3] += up2(v.w);
}
__device__ __forceinline__ void acc4p(uint2 v, f32x2 a[2]) {
    a[0] += up2(v.x); a[1] += up2(v.y);
}

// ================= fused prep: hist(+rank) || x->bf16 || wfrag(W1,W2,W3) =================
// counts must be zeroed beforehand (hipMemsetAsync). hist atomicAdd's RETURN VALUE
// is the edge's within-node rank -> atomic-free CSR placement later.

__device__ __forceinline__ void conv_body(const float* __restrict__ in,
                                          unsigned short* __restrict__ out, int i, int n4) {
    if (i < n4) {
        float4 v = ((const float4*)in)[i];
        ushort4 o;
        o.x = f2bf(v.x); o.y = f2bf(v.y); o.z = f2bf(v.z); o.w = f2bf(v.w);
        ((ushort4*)out)[i] = o;
    }
}

// W[Nw,256] fp32 -> fragment-ordered bf16:
// ushort addr = ((jt*8+kk)*64 + q*16 + lm)*8 + e,  n=jt*16+lm, k=kk*32+q*8+e
__device__ __forceinline__ void wfrag_body(const float* __restrict__ Wf,
                                           unsigned short* __restrict__ out, int idx, int n4) {
    if (idx >= n4) return;
    int n = idx >> 6;
    int k = (idx & 63) << 2;
    float4 v = ((const float4*)Wf)[idx];
    int jt = n >> 4, lm = n & 15, kk = k >> 5, q = (k >> 3) & 3, e = k & 7;
    int off = ((jt * 8 + kk) * 64 + q * 16 + lm) * 8 + e;
    ushort4 o;
    o.x = f2bf(v.x); o.y = f2bf(v.y); o.z = f2bf(v.z); o.w = f2bf(v.w);
    *(ushort4*)(out + off) = o;
}

#define PREP_HIST_B   3125          // 800000/256
#define PREP_CONV_B   12500         // 3200000/256
#define PREP_W1_B     64
#define PREP_W2_B     64
#define PREP_W3_B     16
#define PREP_TOTAL_B  (PREP_HIST_B + PREP_CONV_B + PREP_W1_B + PREP_W2_B + PREP_W3_B)

__global__ __launch_bounds__(256) void prep0_kernel(
        const float* __restrict__ x, unsigned short* __restrict__ xb,
        const float* __restrict__ W1, unsigned short* __restrict__ W1f,
        const float* __restrict__ W2, unsigned short* __restrict__ W2f,
        const float* __restrict__ W3, unsigned short* __restrict__ W3f,
        const int* __restrict__ dst, int* __restrict__ counts,
        unsigned short* __restrict__ rank) {
    int b = blockIdx.x, tid = threadIdx.x;
    if (b < PREP_HIST_B) {
        int e = b * 256 + tid;
        if (e < E_EDGES) {
            int d = dst[e];
            rank[e] = (unsigned short)atomicAdd(&counts[d], 1);
        }
    } else if (b < PREP_HIST_B + PREP_CONV_B) {
        conv_body(x, xb, (b - PREP_HIST_B) * 256 + tid, N_NODES * 256 / 4);
    } else if (b < PREP_HIST_B + PREP_CONV_B + PREP_W1_B) {
        wfrag_body(W1, W1f, (b - PREP_HIST_B - PREP_CONV_B) * 256 + tid, 16384);
    } else if (b < PREP_HIST_B + PREP_CONV_B + PREP_W1_B + PREP_W2_B) {
        wfrag_body(W2, W2f, (b - PREP_HIST_B - PREP_CONV_B - PREP_W1_B) * 256 + tid, 16384);
    } else {
        wfrag_body(W3, W3f, (b - PREP_HIST_B - PREP_CONV_B - PREP_W1_B - PREP_W2_B) * 256 + tid, 4096);
    }
}

// ================= scan (dinv fused into scan1; scan2 folded into scan3) =================

#define SB 1024
__global__ __launch_bounds__(SB) void scan1_dinv_kernel(const int* __restrict__ counts,
                                                        int* __restrict__ partial,
                                                        int* __restrict__ bsum,
                                                        float* __restrict__ dinv) {
    __shared__ int wsum[16];
    int tid = threadIdx.x, lane = tid & 63, wid = tid >> 6;
    int i = blockIdx.x * SB + tid;
    int v = (i < N_NODES) ? counts[i] : 0;
    int x = v;
    #pragma unroll
    for (int off = 1; off < 64; off <<= 1) {
        int y = __shfl_up(x, off, 64);
        if (lane >= off) x += y;
    }
    if (lane == 63) wsum[wid] = x;
    __syncthreads();
    if (wid == 0) {
        int s = (lane < 16) ? wsum[lane] : 0;
        #pragma unroll
        for (int off = 1; off < 16; off <<= 1) {
            int y = __shfl_up(s, off, 64);
            if (lane >= off) s += y;
        }
        if (lane < 16) wsum[lane] = s;
    }
    __syncthreads();
    int woff = wid ? wsum[wid - 1] : 0;
    if (i < N_NODES) {
        partial[i] = woff + x - v;
        dinv[i] = rsqrtf((float)(v + 1));      // +1 self loop
    }
    if (tid == SB - 1) bsum[blockIdx.x] = woff + x;
}

__global__ __launch_bounds__(256) void scan3b_kernel(int* __restrict__ row_ptr,
                                                     const int* __restrict__ bsum,
                                                     int nb) {
    __shared__ int pref[64];
    int tid = threadIdx.x;
    if (tid < 64) {
        int v = (tid < nb) ? bsum[tid] : 0;
        #pragma unroll
        for (int off = 1; off < 64; off <<= 1) {
            int y = __shfl_up(v, off, 64);
            if (tid >= off) v += y;
        }
        pref[tid] = v;
    }
    __syncthreads();
    int i = blockIdx.x * 256 + tid;
    if (i < N_NODES) {
        int c = i >> 10;
        int off = c ? pref[c - 1] : 0;
        row_ptr[i] += off;
    }
    if (i == 0) row_ptr[N_NODES] = pref[nb - 1];
}

// ================= LDS-free MFMA GEMM (bf16 A; epilogue prescales by dinv[row]) ======
// SLICED=true: C stored slice-major [col/64][row][col%64] (feeds the sliced aggregate;
// per-wave col block is 64-wide so the slice index is wave-constant).

template<int WAVES_M, int WAVES_N, int MT, int NT, bool SLICED>
__device__ __forceinline__ void gemm_frag_body(
        int bx, int by, int tid,
        const unsigned short* __restrict__ Ab,
        const unsigned short* __restrict__ Bf,
        const float* __restrict__ dinv,
        unsigned short* __restrict__ C, int M, int Nc) {
    const int wave = tid >> 6, lane = tid & 63;
    const int lm = lane & 15, q = lane >> 4;
    const int bm = bx * (WAVES_M * MT * 16);
    const int bn = by * (WAVES_N * NT * 16);
    const int wm = (wave / WAVES_N) * (MT * 16);
    const int wn = (wave % WAVES_N) * (NT * 16);
    const int jt0 = (bn + wn) >> 4;

    const unsigned short* arow[MT];
    #pragma unroll
    for (int i = 0; i < MT; ++i) {
        int r = bm + wm + i * 16 + lm;
        if (r >= M) r = M - 1;
        arow[i] = Ab + (size_t)r * 256 + q * 8;
    }

    floatx4 acc[MT][NT] = {};

    #pragma unroll
    for (int kk = 0; kk < 8; ++kk) {
        bf16x8 a[MT], b[NT];
        #pragma unroll
        for (int i = 0; i < MT; ++i)
            a[i] = *(const bf16x8*)(arow[i] + kk * 32);
        #pragma unroll
        for (int j = 0; j < NT; ++j)
            b[j] = *(const bf16x8*)(Bf + (((jt0 + j) * 8 + kk) * 64 + lane) * 8);
        #pragma unroll
        for (int i = 0; i < MT; ++i)
            #pragma unroll
            for (int j = 0; j < NT; ++j)
                acc[i][j] = __builtin_amdgcn_mfma_f32_16x16x32_bf16(a[i], b[j], acc[i][j], 0, 0, 0);
    }

    #pragma unroll
    for (int i = 0; i < MT; ++i) {
        int rb = bm + wm + i * 16 + q * 4;
        #pragma unroll
        for (int r = 0; r < 4; ++r) {
            int row = rb + r;
            if (row < M) {
                float dd = dinv[row];
                #pragma unroll
                for (int j = 0; j < NT; ++j) {
                    int col = bn + wn + j * 16 + lm;
                    size_t addr = SLICED
                        ? ((size_t)(col >> 6) * SS + (size_t)row * 64 + (col & 63))
                        : ((size_t)row * Nc + col);
                    C[addr] = f2bf(acc[i][j][r] * dd);
                }
            }
        }
    }
}

__global__ __launch_bounds__(256) void gemm256_kernel(
        const unsigned short* __restrict__ Ab, const unsigned short* __restrict__ Bf,
        const float* __restrict__ dinv, unsigned short* __restrict__ C, int M, int Nc) {
    gemm_frag_body<2, 2, 4, 4, true>(blockIdx.x, blockIdx.y, threadIdx.x, Ab, Bf, dinv, C, M, Nc);
}

__global__ __launch_bounds__(256) void gemm64_kernel(
        const unsigned short* __restrict__ Ab, const unsigned short* __restrict__ Bf,
        const float* __restrict__ dinv, unsigned short* __restrict__ C, int M, int Nc) {
    gemm_frag_body<4, 1, 4, 4, false>(blockIdx.x, 0, threadIdx.x, Ab, Bf, dinv, C, M, Nc);
}

// layer-1 GEMM fused with atomic-free CSR placement: pos = row_ptr[dst[e]] + rank[e]
#define GEMM1_B 782
__global__ __launch_bounds__(256) void gemm1_place_kernel(
        const unsigned short* __restrict__ Ab, const unsigned short* __restrict__ Bf,
        const float* __restrict__ dinv, unsigned short* __restrict__ C, int M, int Nc,
        const int* __restrict__ src, const int* __restrict__ dst,
        const int* __restrict__ row_ptr, const unsigned short* __restrict__ rank,
        int* __restrict__ col_idx) {
    int b = blockIdx.x;
    if (b < PREP_HIST_B) {
        int e = b * 256 + threadIdx.x;
        if (e < E_EDGES) {
            int d = dst[e];
            col_idx[row_ptr[d] + (int)rank[e]] = src[e];
        }
    } else {
        int b2 = b - PREP_HIST_B;
        gemm_frag_body<2, 2, 4, 4, true>(b2 >> 1, b2 & 1, threadIdx.x, Ab, Bf, dinv, C, M, Nc);
    }
}

// ================= column-sliced aggregate =================
// hs is slice-major [4][N][64 cols] (128B rows). blockIdx.y = slice; per XCD the
// slice working set (~5.5MB) is ~L2-resident -> gathers become L2 hits instead
// of L3 spills. 8 lanes/row -> 16 edges in flight per unrolled iteration.
// All __shfl run with full EXEC (wave-uniform guards; divergence only on gathers).
// out[d] = act( dinv[d]*( sum_{s in N(d)} hs[s] + hs[d] ) + b )

template<bool ACT>
__global__ __launch_bounds__(256) void agg256_kernel(
        const int* __restrict__ row_ptr, const int* __restrict__ col_idx,
        const float* __restrict__ dinv, const unsigned short* __restrict__ hs,
        const float* __restrict__ bias,
        float* __restrict__ out, unsigned short* __restrict__ outb) {
    int node = __builtin_amdgcn_readfirstlane(blockIdx.x * 4 + (threadIdx.x >> 6));
    int slice = blockIdx.y;
    const unsigned short* hsl = hs + (size_t)slice * SS;
    int lane = threadIdx.x & 63;
    int g = lane >> 3, sl = lane & 7;   // 8 lanes cover a 128B slice row; 8 edge groups

    f32x2 a[4] = {};

    int beg = row_ptr[node], end = row_ptr[node + 1];
    for (int cbeg = beg; cbeg < end; cbeg += 64) {
        int clen = end - cbeg; if (clen > 64) clen = 64;
        int cidx = (lane < clen) ? col_idx[cbeg + lane] : 0;   // one coalesced load

        int jj = 0;
        for (; jj + 16 <= clen; jj += 16) {        // 16 edges in flight
            int s0 = __shfl(cidx, jj + g);
            int s1 = __shfl(cidx, jj + 8 + g);
            uint4 v0 = ((const uint4*)(hsl + (size_t)s0 * 64))[sl];
            uint4 v1 = ((const uint4*)(hsl + (size_t)s1 * 64))[sl];
            acc8p(v0, a); acc8p(v1, a);
        }
        for (; jj + 8 <= clen; jj += 8) {
            int s = __shfl(cidx, jj + g);
            uint4 v = ((const uint4*)(hsl + (size_t)s * 64))[sl];
            acc8p(v, a);
        }
        int rem = clen - jj;
        if (rem > 0) {                      // uniform guard
            int s = __shfl(cidx, jj + g);   // all lanes shfl (dummy cidx=0 safe)
            if (g < rem) {                  // divergence only around the gather
                uint4 v = ((const uint4*)(hsl + (size_t)s * 64))[sl];
                acc8p(v, a);
            }
        }
    }

    float s0 = a[0].x, s1 = a[0].y, s2 = a[1].x, s3 = a[1].y;
    float s4 = a[2].x, s5 = a[2].y, s6 = a[3].x, s7 = a[3].y;

    // combine the 8 edge groups (masks 8/16/32 preserve lane&7)
    #pragma unroll
    for (int m = 8; m <= 32; m <<= 1) {
        s0 += __shfl_xor(s0, m); s1 += __shfl_xor(s1, m);
        s2 += __shfl_xor(s2, m); s3 += __shfl_xor(s3, m);
        s4 += __shfl_xor(s4, m); s5 += __shfl_xor(s5, m);
        s6 += __shfl_xor(s6, m); s7 += __shfl_xor(s7, m);
    }

    // self loop (all groups identical afterwards -> consistent)
    uint4 sv = ((const uint4*)(hsl + (size_t)node * 64))[sl];
    s0 += blo(sv.x); s1 += bhi(sv.x);
    s2 += blo(sv.y); s3 += bhi(sv.y);
    s4 += blo(sv.z); s5 += bhi(sv.z);
    s6 += blo(sv.w); s7 += bhi(sv.w);

    float dd = dinv[node];
    const float4 b40 = ((const float4*)bias)[slice * 16 + sl * 2];
    const float4 b41 = ((const float4*)bias)[slice * 16 + sl * 2 + 1];
    float f0 = fmaf(s0, dd, b40.x), f1 = fmaf(s1, dd, b40.y);
    float f2 = fmaf(s2, dd, b40.z), f3 = fmaf(s3, dd, b40.w);
    float f4 = fmaf(s4, dd, b41.x), f5 = fmaf(s5, dd, b41.y);
    float f6 = fmaf(s6, dd, b41.z), f7 = fmaf(s7, dd, b41.w);
    if (ACT) {
        f0 = f0 > 0.f ? f0 : SLOPE * f0;  f1 = f1 > 0.f ? f1 : SLOPE * f1;
        f2 = f2 > 0.f ? f2 : SLOPE * f2;  f3 = f3 > 0.f ? f3 : SLOPE * f3;
        f4 = f4 > 0.f ? f4 : SLOPE * f4;  f5 = f5 > 0.f ? f5 : SLOPE * f5;
        f6 = f6 > 0.f ? f6 : SLOPE * f6;  f7 = f7 > 0.f ? f7 : SLOPE * f7;
    }
    if (g == 0) {   // 8 lanes store 256B fp32 + 128B bf16, contiguous per wave
        float* op = out + (size_t)node * 256 + slice * 64 + sl * 8;
        f32x4 o0 = {f0, f1, f2, f3};
        f32x4 o1 = {f4, f5, f6, f7};
        __builtin_nontemporal_store(o0, (f32x4*)op);
        __builtin_nontemporal_store(o1, (f32x4*)op + 1);
        u32x4 ob;
        ob.x = ((unsigned)f2bf(f1) << 16) | f2bf(f0);
        ob.y = ((unsigned)f2bf(f3) << 16) | f2bf(f2);
        ob.z = ((unsigned)f2bf(f5) << 16) | f2bf(f4);
        ob.w = ((unsigned)f2bf(f7) << 16) | f2bf(f6);
        *(u32x4*)(outb + (size_t)node * 256 + slice * 64 + sl * 8) = ob;  // re-read by next GEMM
    }
}

// agg64: 16 lanes/row, 4 edges per wave-load; register-prefetched (R9-verified).
__global__ __launch_bounds__(256) void agg64_kernel(
        const int* __restrict__ row_ptr, const int* __restrict__ col_idx,
        const float* __restrict__ dinv, const unsigned short* __restrict__ hs,
        const float* __restrict__ bias, float* __restrict__ out) {
    int node = __builtin_amdgcn_readfirstlane(blockIdx.x * 4 + (threadIdx.x >> 6));
    int lane = threadIdx.x & 63;
    int g = lane >> 4, sl = lane & 15;

    f32x2 a[2] = {};

    int beg = row_ptr[node], end = row_ptr[node + 1];
    for (int cbeg = beg; cbeg < end; cbeg += 64) {
        int clen = end - cbeg; if (clen > 64) clen = 64;
        int cidx = (lane < clen) ? col_idx[cbeg + lane] : 0;

        int jj = 0;
        for (; jj + 8 <= clen; jj += 8) {
            int s0 = __shfl(cidx, jj + g);
            int s1 = __shfl(cidx, jj + 4 + g);
            uint2 v0 = ((const uint2*)(hs + (size_t)s0 * 64))[sl];
            uint2 v1 = ((const uint2*)(hs + (size_t)s1 * 64))[sl];
            acc4p(v0, a); acc4p(v1, a);
        }
        for (; jj + 4 <= clen; jj += 4) {
            int s = __shfl(cidx, jj + g);
            uint2 v = ((const uint2*)(hs + (size_t)s * 64))[sl];
            acc4p(v, a);
        }
        int rem = clen - jj;
        if (rem > 0) {
            int s = __shfl(cidx, jj + g);
            if (g < rem) {
                uint2 v = ((const uint2*)(hs + (size_t)s * 64))[sl];
                acc4p(v, a);
            }
        }
    }

    float s0 = a[0].x, s1 = a[0].y, s2 = a[1].x, s3 = a[1].y;

    s0 += __shfl_xor(s0, 16); s0 += __shfl_xor(s0, 32);
    s1 += __shfl_xor(s1, 16); s1 += __shfl_xor(s1, 32);
    s2 += __shfl_xor(s2, 16); s2 += __shfl_xor(s2, 32);
    s3 += __shfl_xor(s3, 16); s3 += __shfl_xor(s3, 32);

    uint2 sv = ((const uint2*)(hs + (size_t)node * 64))[sl];
    s0 += blo(sv.x); s1 += bhi(sv.x);
    s2 += blo(sv.y); s3 += bhi(sv.y);

    float dd = dinv[node];
    const float4 b4 = ((const float4*)bias)[sl];
    f32x4 o;
    o[0] = fmaf(s0, dd, b4.x);
    o[1] = fmaf(s1, dd, b4.y);
    o[2] = fmaf(s2, dd, b4.z);
    o[3] = fmaf(s3, dd, b4.w);
    if (g == 0)
        __builtin_nontemporal_store(o, (f32x4*)(out + (size_t)node * 64) + sl);
}

// ================= launch =================

static inline int cdiv(long long a, long long b) { return (int)((a + b - 1) / b); }

extern "C" void kernel_launch(void* const* d_in, const int* in_sizes, int n_in,
                              void* d_out, int out_size, void* d_ws, size_t ws_size,
                              hipStream_t stream) {
    const float* x  = (const float*)d_in[0];
    const int* ei   = (const int*)d_in[1];
    const float* W1 = (const float*)d_in[2];
    const float* b1 = (const float*)d_in[3];
    const float* W2 = (const float*)d_in[4];
    const float* b2 = (const float*)d_in[5];
    const float* W3 = (const float*)d_in[6];
    const float* b3 = (const float*)d_in[7];

    const int* src = ei;
    const int* dst = ei + E_EDGES;

    char* ws = (char*)d_ws;
    int*   row_ptr = (int*)ws;   ws += 50112 * 4;   // N+1
    float* dinv    = (float*)ws; ws += 50048 * 4;
    int*   bsum    = (int*)ws;   ws += 64 * 4;
    unsigned short* rank = (unsigned short*)ws; ws += (size_t)E_EDGES * 2;
    int*   col_idx = (int*)ws;   ws += (size_t)E_EDGES * 4;
    unsigned short* W1f = (unsigned short*)ws; ws += 65536 * 2;
    unsigned short* W2f = (unsigned short*)ws; ws += 65536 * 2;
    unsigned short* W3f = (unsigned short*)ws; ws += 16384 * 2;
    unsigned short* hb  = (unsigned short*)ws; ws += (size_t)N_NODES * 256 * 2;  // hs (sliced for 256-col layers)
    unsigned short* ob  = (unsigned short*)ws;                                   // bf16 activations (row-major)

    // histogram counters ALIASED into hb: counts' lifetime (memset -> prep0 ->
    // scan1) ends before gemm1_place fully overwrites hb each replay.
    int* counts = (int*)hb;   // 200 KB << 25.6 MB hb region

    float* out1 = (float*)d_out;
    float* out2 = out1 + (size_t)N_NODES * 256;
    float* out3 = out2 + (size_t)N_NODES * 256;

    const int NB = cdiv(N_NODES, SB);   // 49

    // ---- prep: zero counts, then {hist(+rank) || x->bf16 || wfrag x3} ----
    (void)hipMemsetAsync(counts, 0, 50048 * sizeof(int), stream);
    prep0_kernel<<<PREP_TOTAL_B, 256, 0, stream>>>(x, ob, W1, W1f, W2, W2f, W3, W3f,
                                                   dst, counts, rank);

    // ---- scan (dinv fused) ----
    scan1_dinv_kernel<<<NB, SB, 0, stream>>>(counts, row_ptr, bsum, dinv);
    scan3b_kernel<<<cdiv(N_NODES, 256), 256, 0, stream>>>(row_ptr, bsum, NB);

    dim3 g256(cdiv(N_NODES, 128), 2);
    dim3 agg_g(cdiv(N_NODES, 4), 4);    // x: node blocks, y: column slice

    // ---- layer 1: GEMM (sliced C) overlapped with atomic-free CSR placement ----
    gemm1_place_kernel<<<PREP_HIST_B + GEMM1_B, 256, 0, stream>>>(
        ob, W1f, dinv, hb, N_NODES, 256, src, dst, row_ptr, rank, col_idx);
    agg256_kernel<true><<<agg_g, 256, 0, stream>>>(row_ptr, col_idx, dinv, hb, b1, out1, ob);

    // ---- layer 2 ----
    gemm256_kernel<<<g256, 256, 0, stream>>>(ob, W2f, dinv, hb, N_NODES, 256);
    agg256_kernel<true><<<agg_g, 256, 0, stream>>>(row_ptr, col_idx, dinv, hb, b2, out2, ob);

    // ---- layer 3 (no activation) ----
    gemm64_kernel<<<cdiv(N_NODES, 256), 256, 0, stream>>>(ob, W3f, dinv, hb, N_NODES, 64);
    agg64_kernel<<<cdiv(N_NODES, 4), 256, 0, stream>>>(row_ptr, col_idx, dinv, hb, b3, out3);
}

// Round 11
// 420.225 us; speedup vs baseline: 1.0725x; 1.0725x over previous
//
#include <hip/hip_runtime.h>

#define N_NODES 50000
#define E_EDGES 800000
#define SLOPE 0.01f

typedef __attribute__((ext_vector_type(8))) short bf16x8;
typedef __attribute__((ext_vector_type(4))) float floatx4;
typedef __attribute__((ext_vector_type(4))) float f32x4;
typedef __attribute__((ext_vector_type(2))) float f32x2;
typedef __attribute__((ext_vector_type(2))) unsigned int u32x2;

__device__ __forceinline__ unsigned short f2bf(float f) {
    unsigned u = __builtin_bit_cast(unsigned, f);
    unsigned r = (u + 0x7FFFu + ((u >> 16) & 1u)) >> 16;
    return (unsigned short)r;
}
__device__ __forceinline__ float bf2f(unsigned short h) {
    unsigned u = ((unsigned)h) << 16;
    return __builtin_bit_cast(float, u);
}
__device__ __forceinline__ float blo(unsigned u) { return __builtin_bit_cast(float, u << 16); }
__device__ __forceinline__ float bhi(unsigned u) { return __builtin_bit_cast(float, u & 0xFFFF0000u); }
__device__ __forceinline__ f32x2 up2(unsigned u) {
    f32x2 t; t.x = blo(u); t.y = bhi(u); return t;
}

// packed accumulate: v_pk_add_f32
__device__ __forceinline__ void acc8p(uint4 v, f32x2 a[4]) {
    a[0] += up2(v.x); a[1] += up2(v.y); a[2] += up2(v.z); a[3] += up2(v.w);
}
__device__ __forceinline__ void acc4p(uint2 v, f32x2 a[2]) {
    a[0] += up2(v.x); a[1] += up2(v.y);
}

// ================= fused prep: hist(+rank) || x->bf16 || wfrag(W1,W2,W3) =================
// counts must be zeroed beforehand (hipMemsetAsync). hist atomicAdd's RETURN VALUE
// is the edge's within-node rank -> atomic-free CSR placement later.

__device__ __forceinline__ void conv_body(const float* __restrict__ in,
                                          unsigned short* __restrict__ out, int i, int n4) {
    if (i < n4) {
        float4 v = ((const float4*)in)[i];
        ushort4 o;
        o.x = f2bf(v.x); o.y = f2bf(v.y); o.z = f2bf(v.z); o.w = f2bf(v.w);
        ((ushort4*)out)[i] = o;
    }
}

// W[Nw,256] fp32 -> fragment-ordered bf16:
// ushort addr = ((jt*8+kk)*64 + q*16 + lm)*8 + e,  n=jt*16+lm, k=kk*32+q*8+e
__device__ __forceinline__ void wfrag_body(const float* __restrict__ Wf,
                                           unsigned short* __restrict__ out, int idx, int n4) {
    if (idx >= n4) return;
    int n = idx >> 6;
    int k = (idx & 63) << 2;
    float4 v = ((const float4*)Wf)[idx];
    int jt = n >> 4, lm = n & 15, kk = k >> 5, q = (k >> 3) & 3, e = k & 7;
    int off = ((jt * 8 + kk) * 64 + q * 16 + lm) * 8 + e;
    ushort4 o;
    o.x = f2bf(v.x); o.y = f2bf(v.y); o.z = f2bf(v.z); o.w = f2bf(v.w);
    *(ushort4*)(out + off) = o;
}

#define PREP_HIST_B   3125          // 800000/256
#define PREP_CONV_B   12500         // 3200000/256
#define PREP_W1_B     64
#define PREP_W2_B     64
#define PREP_W3_B     16
#define PREP_TOTAL_B  (PREP_HIST_B + PREP_CONV_B + PREP_W1_B + PREP_W2_B + PREP_W3_B)

__global__ __launch_bounds__(256) void prep0_kernel(
        const float* __restrict__ x, unsigned short* __restrict__ xb,
        const float* __restrict__ W1, unsigned short* __restrict__ W1f,
        const float* __restrict__ W2, unsigned short* __restrict__ W2f,
        const float* __restrict__ W3, unsigned short* __restrict__ W3f,
        const int* __restrict__ dst, int* __restrict__ counts,
        unsigned short* __restrict__ rank) {
    int b = blockIdx.x, tid = threadIdx.x;
    if (b < PREP_HIST_B) {
        int e = b * 256 + tid;
        if (e < E_EDGES) {
            int d = dst[e];
            rank[e] = (unsigned short)atomicAdd(&counts[d], 1);
        }
    } else if (b < PREP_HIST_B + PREP_CONV_B) {
        conv_body(x, xb, (b - PREP_HIST_B) * 256 + tid, N_NODES * 256 / 4);
    } else if (b < PREP_HIST_B + PREP_CONV_B + PREP_W1_B) {
        wfrag_body(W1, W1f, (b - PREP_HIST_B - PREP_CONV_B) * 256 + tid, 16384);
    } else if (b < PREP_HIST_B + PREP_CONV_B + PREP_W1_B + PREP_W2_B) {
        wfrag_body(W2, W2f, (b - PREP_HIST_B - PREP_CONV_B - PREP_W1_B) * 256 + tid, 16384);
    } else {
        wfrag_body(W3, W3f, (b - PREP_HIST_B - PREP_CONV_B - PREP_W1_B - PREP_W2_B) * 256 + tid, 4096);
    }
}

// ================= scan (dinv fused into scan1; scan2 folded into scan3) =================

#define SB 1024
__global__ __launch_bounds__(SB) void scan1_dinv_kernel(const int* __restrict__ counts,
                                                        int* __restrict__ partial,
                                                        int* __restrict__ bsum,
                                                        float* __restrict__ dinv) {
    __shared__ int wsum[16];
    int tid = threadIdx.x, lane = tid & 63, wid = tid >> 6;
    int i = blockIdx.x * SB + tid;
    int v = (i < N_NODES) ? counts[i] : 0;
    int x = v;
    #pragma unroll
    for (int off = 1; off < 64; off <<= 1) {
        int y = __shfl_up(x, off, 64);
        if (lane >= off) x += y;
    }
    if (lane == 63) wsum[wid] = x;
    __syncthreads();
    if (wid == 0) {
        int s = (lane < 16) ? wsum[lane] : 0;
        #pragma unroll
        for (int off = 1; off < 16; off <<= 1) {
            int y = __shfl_up(s, off, 64);
            if (lane >= off) s += y;
        }
        if (lane < 16) wsum[lane] = s;
    }
    __syncthreads();
    int woff = wid ? wsum[wid - 1] : 0;
    if (i < N_NODES) {
        partial[i] = woff + x - v;
        dinv[i] = rsqrtf((float)(v + 1));      // +1 self loop
    }
    if (tid == SB - 1) bsum[blockIdx.x] = woff + x;
}

__global__ __launch_bounds__(256) void scan3b_kernel(int* __restrict__ row_ptr,
                                                     const int* __restrict__ bsum,
                                                     int nb) {
    __shared__ int pref[64];
    int tid = threadIdx.x;
    if (tid < 64) {
        int v = (tid < nb) ? bsum[tid] : 0;
        #pragma unroll
        for (int off = 1; off < 64; off <<= 1) {
            int y = __shfl_up(v, off, 64);
            if (tid >= off) v += y;
        }
        pref[tid] = v;
    }
    __syncthreads();
    int i = blockIdx.x * 256 + tid;
    if (i < N_NODES) {
        int c = i >> 10;
        int off = c ? pref[c - 1] : 0;
        row_ptr[i] += off;
    }
    if (i == 0) row_ptr[N_NODES] = pref[nb - 1];
}

// ================= LDS-free MFMA GEMM (bf16 A; epilogue prescales by dinv[row]) ======

template<int WAVES_M, int WAVES_N, int MT, int NT>
__device__ __forceinline__ void gemm_frag_body(
        int bx, int by, int tid,
        const unsigned short* __restrict__ Ab,
        const unsigned short* __restrict__ Bf,
        const float* __restrict__ dinv,
        unsigned short* __restrict__ C, int M, int Nc) {
    const int wave = tid >> 6, lane = tid & 63;
    const int lm = lane & 15, q = lane >> 4;
    const int bm = bx * (WAVES_M * MT * 16);
    const int bn = by * (WAVES_N * NT * 16);
    const int wm = (wave / WAVES_N) * (MT * 16);
    const int wn = (wave % WAVES_N) * (NT * 16);
    const int jt0 = (bn + wn) >> 4;

    const unsigned short* arow[MT];
    #pragma unroll
    for (int i = 0; i < MT; ++i) {
        int r = bm + wm + i * 16 + lm;
        if (r >= M) r = M - 1;
        arow[i] = Ab + (size_t)r * 256 + q * 8;
    }

    floatx4 acc[MT][NT] = {};

    #pragma unroll
    for (int kk = 0; kk < 8; ++kk) {
        bf16x8 a[MT], b[NT];
        #pragma unroll
        for (int i = 0; i < MT; ++i)
            a[i] = *(const bf16x8*)(arow[i] + kk * 32);
        #pragma unroll
        for (int j = 0; j < NT; ++j)
            b[j] = *(const bf16x8*)(Bf + (((jt0 + j) * 8 + kk) * 64 + lane) * 8);
        #pragma unroll
        for (int i = 0; i < MT; ++i)
            #pragma unroll
            for (int j = 0; j < NT; ++j)
                acc[i][j] = __builtin_amdgcn_mfma_f32_16x16x32_bf16(a[i], b[j], acc[i][j], 0, 0, 0);
    }

    #pragma unroll
    for (int i = 0; i < MT; ++i) {
        int rb = bm + wm + i * 16 + q * 4;
        #pragma unroll
        for (int r = 0; r < 4; ++r) {
            int row = rb + r;
            if (row < M) {
                float dd = dinv[row];
                #pragma unroll
                for (int j = 0; j < NT; ++j)
                    C[(size_t)row * Nc + bn + wn + j * 16 + lm] = f2bf(acc[i][j][r] * dd);
            }
        }
    }
}

__global__ __launch_bounds__(256) void gemm256_kernel(
        const unsigned short* __restrict__ Ab, const unsigned short* __restrict__ Bf,
        const float* __restrict__ dinv, unsigned short* __restrict__ C, int M, int Nc) {
    gemm_frag_body<2, 2, 4, 4>(blockIdx.x, blockIdx.y, threadIdx.x, Ab, Bf, dinv, C, M, Nc);
}

__global__ __launch_bounds__(256) void gemm64_kernel(
        const unsigned short* __restrict__ Ab, const unsigned short* __restrict__ Bf,
        const float* __restrict__ dinv, unsigned short* __restrict__ C, int M, int Nc) {
    gemm_frag_body<4, 1, 4, 4>(blockIdx.x, 0, threadIdx.x, Ab, Bf, dinv, C, M, Nc);
}

// layer-1 GEMM fused with atomic-free CSR placement: pos = row_ptr[dst[e]] + rank[e]
#define GEMM1_B 782
__global__ __launch_bounds__(256) void gemm1_place_kernel(
        const unsigned short* __restrict__ Ab, const unsigned short* __restrict__ Bf,
        const float* __restrict__ dinv, unsigned short* __restrict__ C, int M, int Nc,
        const int* __restrict__ src, const int* __restrict__ dst,
        const int* __restrict__ row_ptr, const unsigned short* __restrict__ rank,
        int* __restrict__ col_idx) {
    int b = blockIdx.x;
    if (b < PREP_HIST_B) {
        int e = b * 256 + threadIdx.x;
        if (e < E_EDGES) {
            int d = dst[e];
            col_idx[row_ptr[d] + (int)rank[e]] = src[e];
        }
    } else {
        int b2 = b - PREP_HIST_B;
        gemm_frag_body<2, 2, 4, 4>(b2 >> 1, b2 & 1, threadIdx.x, Ab, Bf, dinv, C, M, Nc);
    }
}

// ================= fused aggregate (register-prefetched neighbor list) =================
// hs rows pre-scaled by dinv[row] in the GEMM epilogue (row-major 512B rows).
// out[d] = act( dinv[d]*( sum_{s in N(d)} hs[s] + hs[d] ) + b )
//
// Per 64-edge chunk, ONE coalesced wave-wide load pulls the neighbor list into
// registers; gather indices come from __shfl (ds_bpermute).
// CORRECTNESS RULE: ds_bpermute reads garbage from EXEC-disabled source lanes,
// so every __shfl executes with ALL 64 lanes active (wave-uniform guards).
// MLP: 16-deep unroll puts 16 edges (a full average node) in flight at once.

template<bool ACT>
__global__ __launch_bounds__(256) void agg256_kernel(
        const int* __restrict__ row_ptr, const int* __restrict__ col_idx,
        const float* __restrict__ dinv, const unsigned short* __restrict__ hs,
        const float* __restrict__ bias,
        float* __restrict__ out, unsigned short* __restrict__ outb) {
    int node = __builtin_amdgcn_readfirstlane(blockIdx.x * 4 + (threadIdx.x >> 6));
    int lane = threadIdx.x & 63;
    int half = lane >> 5, sl = lane & 31;   // lane covers cols sl*8..sl*8+7 of edge (pair+half)

    f32x2 a[4] = {};

    int beg = row_ptr[node], end = row_ptr[node + 1];
    for (int cbeg = beg; cbeg < end; cbeg += 64) {
        int clen = end - cbeg; if (clen > 64) clen = 64;
        int cidx = (lane < clen) ? col_idx[cbeg + lane] : 0;   // one coalesced load

        int jj = 0;
        for (; jj + 16 <= clen; jj += 16) {        // 16 edges in flight (8 per half)
            int s0 = __shfl(cidx, jj + half);
            int s1 = __shfl(cidx, jj + 2 + half);
            int s2 = __shfl(cidx, jj + 4 + half);
            int s3 = __shfl(cidx, jj + 6 + half);
            int s4 = __shfl(cidx, jj + 8 + half);
            int s5 = __shfl(cidx, jj + 10 + half);
            int s6 = __shfl(cidx, jj + 12 + half);
            int s7 = __shfl(cidx, jj + 14 + half);
            uint4 v0 = ((const uint4*)(hs + (size_t)s0 * 256))[sl];
            uint4 v1 = ((const uint4*)(hs + (size_t)s1 * 256))[sl];
            uint4 v2 = ((const uint4*)(hs + (size_t)s2 * 256))[sl];
            uint4 v3 = ((const uint4*)(hs + (size_t)s3 * 256))[sl];
            uint4 v4 = ((const uint4*)(hs + (size_t)s4 * 256))[sl];
            uint4 v5 = ((const uint4*)(hs + (size_t)s5 * 256))[sl];
            uint4 v6 = ((const uint4*)(hs + (size_t)s6 * 256))[sl];
            uint4 v7 = ((const uint4*)(hs + (size_t)s7 * 256))[sl];
            acc8p(v0, a); acc8p(v1, a); acc8p(v2, a); acc8p(v3, a);
            acc8p(v4, a); acc8p(v5, a); acc8p(v6, a); acc8p(v7, a);
        }
        for (; jj + 8 <= clen; jj += 8) {          // 8 edges in flight
            int s0 = __shfl(cidx, jj + half);
            int s1 = __shfl(cidx, jj + 2 + half);
            int s2 = __shfl(cidx, jj + 4 + half);
            int s3 = __shfl(cidx, jj + 6 + half);
            uint4 v0 = ((const uint4*)(hs + (size_t)s0 * 256))[sl];
            uint4 v1 = ((const uint4*)(hs + (size_t)s1 * 256))[sl];
            uint4 v2 = ((const uint4*)(hs + (size_t)s2 * 256))[sl];
            uint4 v3 = ((const uint4*)(hs + (size_t)s3 * 256))[sl];
            acc8p(v0, a); acc8p(v1, a); acc8p(v2, a); acc8p(v3, a);
        }
        for (; jj + 2 <= clen; jj += 2) {          // uniform
            int s = __shfl(cidx, jj + half);
            uint4 v = ((const uint4*)(hs + (size_t)s * 256))[sl];
            acc8p(v, a);
        }
        if (jj < clen) {                           // uniform guard
            int s = __shfl(cidx, jj);              // shfl with ALL lanes active
            if (half == 0) {                       // divergence only around the gather
                uint4 v = ((const uint4*)(hs + (size_t)s * 256))[sl];
                acc8p(v, a);
            }
        }
    }

    float s0 = a[0].x, s1 = a[0].y, s2 = a[1].x, s3 = a[1].y;
    float s4 = a[2].x, s5 = a[2].y, s6 = a[3].x, s7 = a[3].y;

    // combine the two halves (each processed half of the edges)
    s0 += __shfl_xor(s0, 32); s1 += __shfl_xor(s1, 32);
    s2 += __shfl_xor(s2, 32); s3 += __shfl_xor(s3, 32);
    s4 += __shfl_xor(s4, 32); s5 += __shfl_xor(s5, 32);
    s6 += __shfl_xor(s6, 32); s7 += __shfl_xor(s7, 32);

    // self loop (both halves add identically -> stays consistent)
    uint4 sv = ((const uint4*)(hs + (size_t)node * 256))[sl];
    s0 += blo(sv.x); s1 += bhi(sv.x);
    s2 += blo(sv.y); s3 += bhi(sv.y);
    s4 += blo(sv.z); s5 += bhi(sv.z);
    s6 += blo(sv.w); s7 += bhi(sv.w);

    // redistribute: lane l wants cols 4l..4l+3, held by lane l>>1, elems (l&1)*4..+3
    int srcl = lane >> 1;
    float t0 = __shfl(s0, srcl), t1 = __shfl(s1, srcl);
    float t2 = __shfl(s2, srcl), t3 = __shfl(s3, srcl);
    float t4 = __shfl(s4, srcl), t5 = __shfl(s5, srcl);
    float t6 = __shfl(s6, srcl), t7 = __shfl(s7, srcl);
    bool hi = (lane & 1);
    float f0 = hi ? t4 : t0, f1 = hi ? t5 : t1, f2 = hi ? t6 : t2, f3 = hi ? t7 : t3;

    float dd = dinv[node];
    const float4 b4 = ((const float4*)bias)[lane];
    f0 = fmaf(f0, dd, b4.x); f1 = fmaf(f1, dd, b4.y);
    f2 = fmaf(f2, dd, b4.z); f3 = fmaf(f3, dd, b4.w);
    if (ACT) {
        f0 = f0 > 0.f ? f0 : SLOPE * f0;
        f1 = f1 > 0.f ? f1 : SLOPE * f1;
        f2 = f2 > 0.f ? f2 : SLOPE * f2;
        f3 = f3 > 0.f ? f3 : SLOPE * f3;
    }
    f32x4 o = {f0, f1, f2, f3};
    __builtin_nontemporal_store(o, (f32x4*)(out + (size_t)node * 256) + lane);
    u32x2 obv;
    obv.x = ((unsigned)f2bf(f1) << 16) | f2bf(f0);
    obv.y = ((unsigned)f2bf(f3) << 16) | f2bf(f2);
    ((u32x2*)(outb + (size_t)node * 256))[lane] = obv;   // re-read by next GEMM
}

// agg64: 16 lanes/row, 4 edges per wave-load; register-prefetched (R9-verified).
__global__ __launch_bounds__(256) void agg64_kernel(
        const int* __restrict__ row_ptr, const int* __restrict__ col_idx,
        const float* __restrict__ dinv, const unsigned short* __restrict__ hs,
        const float* __restrict__ bias, float* __restrict__ out) {
    int node = __builtin_amdgcn_readfirstlane(blockIdx.x * 4 + (threadIdx.x >> 6));
    int lane = threadIdx.x & 63;
    int g = lane >> 4, sl = lane & 15;

    f32x2 a[2] = {};

    int beg = row_ptr[node], end = row_ptr[node + 1];
    for (int cbeg = beg; cbeg < end; cbeg += 64) {
        int clen = end - cbeg; if (clen > 64) clen = 64;
        int cidx = (lane < clen) ? col_idx[cbeg + lane] : 0;

        int jj = 0;
        for (; jj + 8 <= clen; jj += 8) {
            int s0 = __shfl(cidx, jj + g);
            int s1 = __shfl(cidx, jj + 4 + g);
            uint2 v0 = ((const uint2*)(hs + (size_t)s0 * 64))[sl];
            uint2 v1 = ((const uint2*)(hs + (size_t)s1 * 64))[sl];
            acc4p(v0, a); acc4p(v1, a);
        }
        for (; jj + 4 <= clen; jj += 4) {
            int s = __shfl(cidx, jj + g);
            uint2 v = ((const uint2*)(hs + (size_t)s * 64))[sl];
            acc4p(v, a);
        }
        int rem = clen - jj;
        if (rem > 0) {                      // uniform guard
            int s = __shfl(cidx, jj + g);   // ALL lanes shfl (dummy cidx=0 safe)
            if (g < rem) {                  // divergence only around the gather
                uint2 v = ((const uint2*)(hs + (size_t)s * 64))[sl];
                acc4p(v, a);
            }
        }
    }

    float s0 = a[0].x, s1 = a[0].y, s2 = a[1].x, s3 = a[1].y;

    s0 += __shfl_xor(s0, 16); s0 += __shfl_xor(s0, 32);
    s1 += __shfl_xor(s1, 16); s1 += __shfl_xor(s1, 32);
    s2 += __shfl_xor(s2, 16); s2 += __shfl_xor(s2, 32);
    s3 += __shfl_xor(s3, 16); s3 += __shfl_xor(s3, 32);

    uint2 sv = ((const uint2*)(hs + (size_t)node * 64))[sl];
    s0 += blo(sv.x); s1 += bhi(sv.x);
    s2 += blo(sv.y); s3 += bhi(sv.y);

    float dd = dinv[node];
    const float4 b4 = ((const float4*)bias)[sl];
    f32x4 o;
    o[0] = fmaf(s0, dd, b4.x);
    o[1] = fmaf(s1, dd, b4.y);
    o[2] = fmaf(s2, dd, b4.z);
    o[3] = fmaf(s3, dd, b4.w);
    if (g == 0)
        __builtin_nontemporal_store(o, (f32x4*)(out + (size_t)node * 64) + sl);
}

// ================= launch =================

static inline int cdiv(long long a, long long b) { return (int)((a + b - 1) / b); }

extern "C" void kernel_launch(void* const* d_in, const int* in_sizes, int n_in,
                              void* d_out, int out_size, void* d_ws, size_t ws_size,
                              hipStream_t stream) {
    const float* x  = (const float*)d_in[0];
    const int* ei   = (const int*)d_in[1];
    const float* W1 = (const float*)d_in[2];
    const float* b1 = (const float*)d_in[3];
    const float* W2 = (const float*)d_in[4];
    const float* b2 = (const float*)d_in[5];
    const float* W3 = (const float*)d_in[6];
    const float* b3 = (const float*)d_in[7];

    const int* src = ei;
    const int* dst = ei + E_EDGES;

    char* ws = (char*)d_ws;
    int*   row_ptr = (int*)ws;   ws += 50112 * 4;   // N+1
    float* dinv    = (float*)ws; ws += 50048 * 4;
    int*   bsum    = (int*)ws;   ws += 64 * 4;
    unsigned short* rank = (unsigned short*)ws; ws += (size_t)E_EDGES * 2;
    int*   col_idx = (int*)ws;   ws += (size_t)E_EDGES * 4;
    unsigned short* W1f = (unsigned short*)ws; ws += 65536 * 2;
    unsigned short* W2f = (unsigned short*)ws; ws += 65536 * 2;
    unsigned short* W3f = (unsigned short*)ws; ws += 16384 * 2;
    unsigned short* hb  = (unsigned short*)ws; ws += (size_t)N_NODES * 256 * 2;  // hs (prescaled)
    unsigned short* ob  = (unsigned short*)ws;                                   // bf16 activations

    // histogram counters ALIASED into hb: counts' lifetime (memset -> prep0 ->
    // scan1) ends before gemm1_place fully overwrites hb each replay.
    int* counts = (int*)hb;   // 200 KB << 25.6 MB hb region

    float* out1 = (float*)d_out;
    float* out2 = out1 + (size_t)N_NODES * 256;
    float* out3 = out2 + (size_t)N_NODES * 256;

    const int NB = cdiv(N_NODES, SB);   // 49

    // ---- prep: zero counts, then {hist(+rank) || x->bf16 || wfrag x3} ----
    (void)hipMemsetAsync(counts, 0, 50048 * sizeof(int), stream);
    prep0_kernel<<<PREP_TOTAL_B, 256, 0, stream>>>(x, ob, W1, W1f, W2, W2f, W3, W3f,
                                                   dst, counts, rank);

    // ---- scan (dinv fused) ----
    scan1_dinv_kernel<<<NB, SB, 0, stream>>>(counts, row_ptr, bsum, dinv);
    scan3b_kernel<<<cdiv(N_NODES, 256), 256, 0, stream>>>(row_ptr, bsum, NB);

    dim3 g256(cdiv(N_NODES, 128), 2);
    int agg_grid = cdiv(N_NODES, 4);

    // ---- layer 1: GEMM overlapped with atomic-free CSR placement ----
    gemm1_place_kernel<<<PREP_HIST_B + GEMM1_B, 256, 0, stream>>>(
        ob, W1f, dinv, hb, N_NODES, 256, src, dst, row_ptr, rank, col_idx);
    agg256_kernel<true><<<agg_grid, 256, 0, stream>>>(row_ptr, col_idx, dinv, hb, b1, out1, ob);

    // ---- layer 2 ----
    gemm256_kernel<<<g256, 256, 0, stream>>>(ob, W2f, dinv, hb, N_NODES, 256);
    agg256_kernel<true><<<agg_grid, 256, 0, stream>>>(row_ptr, col_idx, dinv, hb, b2, out2, ob);

    // ---- layer 3 (no activation) ----
    gemm64_kernel<<<cdiv(N_NODES, 256), 256, 0, stream>>>(ob, W3f, dinv, hb, N_NODES, 64);
    agg64_kernel<<<agg_grid, 256, 0, stream>>>(row_ptr, col_idx, dinv, hb, b3, out3);
}